// Round 3
// 800.059 us; speedup vs baseline: 1.2403x; 1.2403x over previous
//
#include <hip/hip_runtime.h>

typedef unsigned short u16;
typedef unsigned int   u32;

// B=512 N=196 C=384 H=12 D=32 A=49 W=14, 3C=1152
#define SCALE 0.17677669529663687f

using bf16x8 = __attribute__((ext_vector_type(8))) __bf16;
using f32x4  = __attribute__((ext_vector_type(4))) float;

__device__ __forceinline__ float bf2f(u16 u) {
  union { u32 i; float f; } c; c.i = ((u32)u) << 16; return c.f;
}
__device__ __forceinline__ u16 f2bf(float f) {
  union { float f; u32 i; } c; c.f = f;
  u32 x = c.i;
  return (u16)((x + 0x7fffu + ((x >> 16) & 1u)) >> 16);
}

// async global->LDS, 16B per lane (GEMM staging)
__device__ __forceinline__ void gl_lds16(const void* g, void* l) {
  __builtin_amdgcn_global_load_lds(
      (__attribute__((address_space(1))) void*)(uintptr_t)g,
      (__attribute__((address_space(3))) void*)(uintptr_t)l, 16, 0, 0);
}

// 16B LDS fragment load via two 8B reads (rows are 8B- but not 16B-aligned)
__device__ __forceinline__ bf16x8 lds8(const u16* p) {
  union { bf16x8 v; uint2 u[2]; } r;
  r.u[0] = *(const uint2*)p;
  r.u[1] = *(const uint2*)(p + 4);
  return r.v;
}

// ---------------- bias precompute ----------------
__device__ __forceinline__ void lin_w(int i, int& i0, int& i1, float& w0, float& w1) {
  if (i == 0)       { i0 = 0; i1 = 0; w0 = 1.f;  w1 = 0.f;  }
  else if (i == 13) { i0 = 6; i1 = 6; w0 = 1.f;  w1 = 0.f;  }
  else if (i & 1)   { int j = i >> 1; i0 = j;     i1 = j + 1; w0 = 0.75f; w1 = 0.25f; }
  else              { int j = i >> 1; i0 = j - 1; i1 = j;     w0 = 0.25f; w1 = 0.75f; }
}

__global__ void k_bias1(const float* __restrict__ an, const float* __restrict__ ah,
                        const float* __restrict__ aw, float* __restrict__ out) {
  int idx = blockIdx.x * 256 + threadIdx.x;
  if (idx >= 12 * 49 * 196) return;
  int n = idx % 196; int a = (idx / 196) % 49; int h = idx / (196 * 49);
  int y = n / 14, x = n % 14;
  int y0, y1, x0, x1; float wy0, wy1, wx0, wx1;
  lin_w(y, y0, y1, wy0, wy1); lin_w(x, x0, x1, wx0, wx1);
  const float* p = an + (h * 49 + a) * 49;
  float v = wy0 * (wx0 * p[y0 * 7 + x0] + wx1 * p[y0 * 7 + x1])
          + wy1 * (wx0 * p[y1 * 7 + x0] + wx1 * p[y1 * 7 + x1]);
  v += ah[(h * 49 + a) * 14 + y] + aw[(h * 49 + a) * 14 + x];
  out[idx] = v;
}

__global__ void k_bias2(const float* __restrict__ na, const float* __restrict__ ha,
                        const float* __restrict__ wa, float* __restrict__ out) {
  int idx = blockIdx.x * 256 + threadIdx.x;
  if (idx >= 12 * 196 * 49) return;
  int a = idx % 49; int n = (idx / 49) % 196; int h = idx / (49 * 196);
  int y = n / 14, x = n % 14;
  int y0, y1, x0, x1; float wy0, wy1, wx0, wx1;
  lin_w(y, y0, y1, wy0, wy1); lin_w(x, x0, x1, wx0, wx1);
  const float* p = na + (h * 49 + a) * 49;
  float v = wy0 * (wx0 * p[y0 * 7 + x0] + wx1 * p[y0 * 7 + x1])
          + wy1 * (wx0 * p[y1 * 7 + x0] + wx1 * p[y1 * 7 + x1]);
  v += ha[(h * 14 + y) * 49 + a] + wa[(h * 14 + x) * 49 + a];
  out[idx] = v;
}

// ---------------- fp32 -> bf16 conversion ----------------
__global__ void k_f2bf(const float* __restrict__ src, u16* __restrict__ dst, long n) {
  long i = ((long)blockIdx.x * 256 + threadIdx.x) * 8;
  if (i >= n) return;
  float4 a = *(const float4*)(src + i);
  float4 b = *(const float4*)(src + i + 4);
  union { u16 s[8]; uint4 v; } pk;
  pk.s[0] = f2bf(a.x); pk.s[1] = f2bf(a.y); pk.s[2] = f2bf(a.z); pk.s[3] = f2bf(a.w);
  pk.s[4] = f2bf(b.x); pk.s[5] = f2bf(b.y); pk.s[6] = f2bf(b.z); pk.s[7] = f2bf(b.w);
  *(uint4*)(dst + i) = pk.v;
}

// ---------------- MFMA GEMM: qkv = xb @ wqkv^T (bf16 out) ----------------
__global__ __launch_bounds__(256) void k_mfma_qkv(const u16* __restrict__ A,
    const u16* __restrict__ Bw, u16* __restrict__ out) {
  __shared__ __align__(16) u16 As[128 * 64];
  __shared__ __align__(16) u16 Bs[128 * 64];
  const int tid = threadIdx.x;
  const int lane = tid & 63, w = tid >> 6;
  const int wm = (w >> 1) * 64, wn = (w & 1) * 64;
  const long row0 = (long)blockIdx.y * 128;
  const int col0 = blockIdx.x * 128;
  const int quad = lane >> 4, m16 = lane & 15;
  f32x4 acc[4][4] = {};
  for (int kt = 0; kt < 6; ++kt) {
    const int k0 = kt * 64;
    __syncthreads();
#pragma unroll
    for (int i = 0; i < 4; ++i) {
      int c = i * 256 + w * 64 + lane;
      const u16* ga = A + (row0 + (c >> 3)) * 384 + k0 + (c & 7) * 8;
      gl_lds16(ga, &As[(i * 256 + w * 64) * 8]);
      const u16* gb = Bw + (long)(col0 + (c >> 3)) * 384 + k0 + (c & 7) * 8;
      gl_lds16(gb, &Bs[(i * 256 + w * 64) * 8]);
    }
    __syncthreads();
#pragma unroll
    for (int kk = 0; kk < 2; ++kk) {
      bf16x8 av[4], bv[4];
#pragma unroll
      for (int i = 0; i < 4; ++i)
        av[i] = *(const bf16x8*)&As[(wm + i * 16 + m16) * 64 + kk * 32 + quad * 8];
#pragma unroll
      for (int j = 0; j < 4; ++j)
        bv[j] = *(const bf16x8*)&Bs[(wn + j * 16 + m16) * 64 + kk * 32 + quad * 8];
#pragma unroll
      for (int i = 0; i < 4; ++i)
#pragma unroll
        for (int j = 0; j < 4; ++j)
          acc[i][j] = __builtin_amdgcn_mfma_f32_16x16x32_bf16(av[i], bv[j], acc[i][j], 0, 0, 0);
    }
  }
#pragma unroll
  for (int i = 0; i < 4; ++i)
#pragma unroll
    for (int r = 0; r < 4; ++r) {
      long row = row0 + wm + i * 16 + quad * 4 + r;
      u16* op = out + row * 1152 + col0 + wn + m16;
#pragma unroll
      for (int j = 0; j < 4; ++j) op[j * 16] = f2bf(acc[i][j][r]);
    }
}

// ---------------- MFMA GEMM: out = t @ proj^T + pb (fp32 out) ----------------
__global__ __launch_bounds__(256) void k_mfma_out(const u16* __restrict__ A,
    const u16* __restrict__ Bw, const float* __restrict__ pb, float* __restrict__ out) {
  __shared__ __align__(16) u16 As[128 * 64];
  __shared__ __align__(16) u16 Bs[128 * 64];
  const int tid = threadIdx.x;
  const int lane = tid & 63, w = tid >> 6;
  const int wm = (w >> 1) * 64, wn = (w & 1) * 64;
  const long row0 = (long)blockIdx.y * 128;
  const int col0 = blockIdx.x * 128;
  const int quad = lane >> 4, m16 = lane & 15;
  f32x4 acc[4][4] = {};
  for (int kt = 0; kt < 6; ++kt) {
    const int k0 = kt * 64;
    __syncthreads();
#pragma unroll
    for (int i = 0; i < 4; ++i) {
      int c = i * 256 + w * 64 + lane;
      const u16* ga = A + (row0 + (c >> 3)) * 384 + k0 + (c & 7) * 8;
      gl_lds16(ga, &As[(i * 256 + w * 64) * 8]);
      const u16* gb = Bw + (long)(col0 + (c >> 3)) * 384 + k0 + (c & 7) * 8;
      gl_lds16(gb, &Bs[(i * 256 + w * 64) * 8]);
    }
    __syncthreads();
#pragma unroll
    for (int kk = 0; kk < 2; ++kk) {
      bf16x8 av[4], bv[4];
#pragma unroll
      for (int i = 0; i < 4; ++i)
        av[i] = *(const bf16x8*)&As[(wm + i * 16 + m16) * 64 + kk * 32 + quad * 8];
#pragma unroll
      for (int j = 0; j < 4; ++j)
        bv[j] = *(const bf16x8*)&Bs[(wn + j * 16 + m16) * 64 + kk * 32 + quad * 8];
#pragma unroll
      for (int i = 0; i < 4; ++i)
#pragma unroll
        for (int j = 0; j < 4; ++j)
          acc[i][j] = __builtin_amdgcn_mfma_f32_16x16x32_bf16(av[i], bv[j], acc[i][j], 0, 0, 0);
    }
  }
  float pbv[4];
#pragma unroll
  for (int j = 0; j < 4; ++j) pbv[j] = pb[col0 + wn + j * 16 + m16];
#pragma unroll
  for (int i = 0; i < 4; ++i)
#pragma unroll
    for (int r = 0; r < 4; ++r) {
      long row = row0 + wm + i * 16 + quad * 4 + r;
      float* op = out + row * 384 + col0 + wn + m16;
#pragma unroll
      for (int j = 0; j < 4; ++j) op[j * 16] = acc[i][j][r] + pbv[j];
    }
}

// ---------------- fused pool + agent-attn + q-attn + dwc ----------------
// block = (b,h), 256 threads (4 waves). LDS = 39808 B -> 4 blocks/CU (16 waves).
//  * B+C fused: unnormalized exp tiles accumulate straight into the AV MFMA
//    (per-wave 16x32 transpose scratch), row-scale by 1/sum at the end.
//    inv[] is ZEROED for padding agents >=49 (rs==0 there; 1/0*0 = NaN poisoned
//    AVt cols 49..63 in the previous rev — 0*NaN propagates through MFMA).
//  * K read directly from global (L1/L2-hot); Ks staging gone.
//  * P2 per-wave, overlaid on dead Vs. 2 barriers total.
// Liveness:  scr  (BC, per-wave)        @0      4608
//            dwcs (C2 -> E)             @4608   12544
//            AVt  (end-BC -> E)         @17152  4352
//            Vs   (A -> C2)             @21504  14112
//            P2w  (D/E, per-wave)       @21504  8704 (over dead Vs)
//            ags  (A -> D, 49 rows)     @35616  3528
//            dwcw (A -> C2)             @39144  640
#define OFF_SCR   0
#define OFF_DWCS  4608
#define OFF_AVT   17152
#define OFF_VS    21504
#define OFF_P2    21504
#define OFF_AGS   35616
#define OFF_DWCW  39144
#define SMEM_BYTES 39808

__global__ __launch_bounds__(256, 4) void k_fused(const u16* __restrict__ qkv,
    const float* __restrict__ bias1, const float* __restrict__ bias2,
    const float* __restrict__ dwc_w, const float* __restrict__ dwc_b,
    u16* __restrict__ t) {
  __shared__ __align__(16) char smem[SMEM_BYTES];
  u16* AVt  = (u16*)(smem + OFF_AVT);
  u16* dwcs = (u16*)(smem + OFF_DWCS);
  u16* Vs   = (u16*)(smem + OFF_VS);
  u16* ags  = (u16*)(smem + OFF_AGS);
  u16* dwcw = (u16*)(smem + OFF_DWCW);

  const int bh = blockIdx.x, b = bh / 12, h = bh % 12;
  const int tid = threadIdx.x;
  const int lane = tid & 63, w = tid >> 6;
  const int quad = lane >> 4, m16 = lane & 15;
  u16* scr = (u16*)(smem + OFF_SCR) + w * 576;    // [16][36] u16 per wave
  u16* P2w = (u16*)(smem + OFF_P2)  + w * 1088;   // [16][68] u16 per wave
  const long qkvb = (long)b * 196 * 1152;
  const f32x4 zf = {0.f, 0.f, 0.f, 0.f};

  // ===== Phase A: stage V, dwc weights, pooled agents =====
  if (tid < 196) {
    const uint2* v2p = (const uint2*)(qkv + qkvb + (long)tid * 1152 + 768 + h * 32);
    uint2* vd = (uint2*)&Vs[tid * 36];
#pragma unroll
    for (int i = 0; i < 8; ++i) vd[i] = v2p[i];
  }
  for (int i = tid; i < 320; i += 256) {
    int tap = i >> 5, ch = i & 31;
    float v = (tap < 9) ? dwc_w[(h * 32 + ch) * 9 + tap] : dwc_b[h * 32 + ch];
    dwcw[tap * 32 + ch] = f2bf(v);
  }
  for (int i = tid; i < 784; i += 256) {  // 49 agents x 16 ch-pairs
    int a = i >> 4, cp = i & 15;
    int ay = a / 7, ax = a % 7;
    int y0 = ay * 2, x0 = ax * 2;
    const u16* q0 = qkv + qkvb + h * 32 + cp * 2;
    u32 v00 = *(const u32*)(q0 + (long)(y0 * 14 + x0) * 1152);
    u32 v01 = *(const u32*)(q0 + (long)(y0 * 14 + x0 + 1) * 1152);
    u32 v10 = *(const u32*)(q0 + (long)((y0 + 1) * 14 + x0) * 1152);
    u32 v11 = *(const u32*)(q0 + (long)((y0 + 1) * 14 + x0 + 1) * 1152);
    float lo = 0.25f * (bf2f((u16)(v00 & 0xffff)) + bf2f((u16)(v01 & 0xffff))
                      + bf2f((u16)(v10 & 0xffff)) + bf2f((u16)(v11 & 0xffff)));
    float hi = 0.25f * (bf2f((u16)(v00 >> 16)) + bf2f((u16)(v01 >> 16))
                      + bf2f((u16)(v10 >> 16)) + bf2f((u16)(v11 >> 16)));
    *(u32*)&ags[a * 36 + cp * 2] = (u32)f2bf(lo) | ((u32)f2bf(hi) << 16);
  }
  __syncthreads();

  // ===== Phase BC: fused S1-softmax-numerator + AV accumulate =====
  // wave w owns agents 16w..16w+15. For each pair of 16-token tiles:
  //   S = mfma(ag, K_global); e = exp(S*SCALE + b1) (unnormalized, masked);
  //   transpose e via per-wave scratch (C-layout -> A-layout);
  //   avacc += mfma(e_tile, V_tile_gather).
  // Finally scale rows by 1/rowsum and write AVt[ch][agent].
  {
    int ar = 16 * w + m16; if (ar > 48) ar = 48;   // clamped: dup rows masked later
    bf16x8 av = lds8(&ags[ar * 36 + quad * 8]);
    const u16* kq = qkv + qkvb + 384 + h * 32 + quad * 8;
    const float* b1 = bias1 + (long)h * 49 * 196;
    f32x4 avacc[2] = {zf, zf};
    float rs[4] = {0.f, 0.f, 0.f, 0.f};
    for (int k7 = 0; k7 < 7; ++k7) {
#pragma unroll
      for (int t2 = 0; t2 < 2; ++t2) {
        int nt = k7 * 2 + t2;
        if (nt < 13) {
          int tk = nt * 16 + m16; if (tk > 195) tk = 195;
          bf16x8 bv = *(const bf16x8*)(kq + (long)tk * 1152);
          f32x4 s = __builtin_amdgcn_mfma_f32_16x16x32_bf16(av, bv, zf, 0, 0, 0);
#pragma unroll
          for (int r = 0; r < 4; ++r) {
            int agent = 16 * w + quad * 4 + r;
            int token = nt * 16 + m16;
            float e = 0.f;
            if (agent < 49 && token < 196)
              e = __expf(s[r] * SCALE + b1[agent * 196 + token]);
            rs[r] += e;
            scr[(quad * 4 + r) * 36 + t2 * 16 + m16] = f2bf(e);
          }
        } else {
#pragma unroll
          for (int r = 0; r < 4; ++r)
            scr[(quad * 4 + r) * 36 + t2 * 16 + m16] = 0;
        }
      }
      bf16x8 ap = lds8(&scr[m16 * 36 + quad * 8]);
#pragma unroll
      for (int ntc = 0; ntc < 2; ++ntc) {
        union { u16 s[8]; bf16x8 v; } bp;
#pragma unroll
        for (int j = 0; j < 8; ++j) {
          int tok = k7 * 32 + quad * 8 + j;
          bp.s[j] = (tok < 196) ? Vs[tok * 36 + ntc * 16 + m16] : (u16)0;
        }
        avacc[ntc] = __builtin_amdgcn_mfma_f32_16x16x32_bf16(ap, bp.v, avacc[ntc], 0, 0, 0);
      }
    }
    float inv[4];
#pragma unroll
    for (int r = 0; r < 4; ++r) {
      rs[r] += __shfl_xor(rs[r], 1);
      rs[r] += __shfl_xor(rs[r], 2);
      rs[r] += __shfl_xor(rs[r], 4);
      rs[r] += __shfl_xor(rs[r], 8);
      // padding agents (>=49) have rs==0; force inv=0 so AVt cols stay 0 (not NaN)
      inv[r] = (16 * w + quad * 4 + r < 49) ? 1.f / rs[r] : 0.f;
    }
#pragma unroll
    for (int ntc = 0; ntc < 2; ++ntc)
#pragma unroll
      for (int r = 0; r < 4; ++r)
        AVt[(ntc * 16 + m16) * 68 + 16 * w + quad * 4 + r] = f2bf(avacc[ntc][r] * inv[r]);
  }

  // ===== Phase C2: depthwise 3x3 from Vs -> dwcs (thread = ch-pair x token-slot) =====
  {
    int cp = tid & 15, slot = tid >> 4;
    float wv[20];
#pragma unroll
    for (int tp = 0; tp < 10; ++tp) {
      u32 ww = *(const u32*)&dwcw[tp * 32 + cp * 2];
      wv[2 * tp] = bf2f((u16)(ww & 0xffff));
      wv[2 * tp + 1] = bf2f((u16)(ww >> 16));
    }
    for (int token = slot; token < 196; token += 16) {
      int y = token / 14, x = token % 14;
      float a0 = wv[18], a1 = wv[19];
      int tap = 0;
      for (int dy = -1; dy <= 1; ++dy) {
        int yy = y + dy;
        for (int dx = -1; dx <= 1; ++dx, ++tap) {
          int xx = x + dx;
          if (yy < 0 || yy > 13 || xx < 0 || xx > 13) continue;
          u32 vv = *(const u32*)&Vs[(yy * 14 + xx) * 36 + cp * 2];
          a0 += wv[2 * tap] * bf2f((u16)(vv & 0xffff));
          a1 += wv[2 * tap + 1] * bf2f((u16)(vv >> 16));
        }
      }
      *(u32*)&dwcs[token * 32 + cp * 2] = (u32)f2bf(a0) | ((u32)f2bf(a1) << 16);
    }
  }
  __syncthreads();  // AVt/dwcs ready for all waves; Vs dead -> P2w region usable

  // ===== Phase D+E: per m-tile: S2 softmax -> P2w -> Out = P2 @ AV (+dwc) -> t =====
  const float* b2 = bias2 + (long)h * 196 * 49;
  for (int mt = w; mt < 13; mt += 4) {
    int tka = mt * 16 + m16; if (tka > 195) tka = 195;
    bf16x8 aq = *(const bf16x8*)(qkv + qkvb + (long)tka * 1152 + h * 32 + quad * 8);
    f32x4 sacc[4];
#pragma unroll
    for (int nt = 0; nt < 4; ++nt) {
      int gr = nt * 16 + m16; if (gr > 48) gr = 48;   // clamped dup, masked below
      bf16x8 bv = lds8(&ags[gr * 36 + quad * 8]);
      sacc[nt] = __builtin_amdgcn_mfma_f32_16x16x32_bf16(aq, bv, zf, 0, 0, 0);
    }
    float rs[4] = {0.f, 0.f, 0.f, 0.f};
#pragma unroll
    for (int nt = 0; nt < 4; ++nt) {
      int agent = nt * 16 + m16;
#pragma unroll
      for (int r = 0; r < 4; ++r) {
        int token = mt * 16 + quad * 4 + r; if (token > 195) token = 195;
        float e = 0.f;
        if (agent < 49)
          e = __expf(sacc[nt][r] * SCALE + b2[token * 49 + agent]);
        sacc[nt][r] = e;
        rs[r] += e;
      }
    }
    float inv[4];
#pragma unroll
    for (int r = 0; r < 4; ++r) {
      rs[r] += __shfl_xor(rs[r], 1);
      rs[r] += __shfl_xor(rs[r], 2);
      rs[r] += __shfl_xor(rs[r], 4);
      rs[r] += __shfl_xor(rs[r], 8);
      inv[r] = 1.f / rs[r];
    }
#pragma unroll
    for (int nt = 0; nt < 4; ++nt)
#pragma unroll
      for (int r = 0; r < 4; ++r)
        P2w[(quad * 4 + r) * 68 + nt * 16 + m16] = f2bf(sacc[nt][r] * inv[r]);
    // Out = P2 @ AV  (same-wave LDS write->read: DS is in-order per wave)
    f32x4 oacc[2] = {zf, zf};
#pragma unroll
    for (int k2 = 0; k2 < 2; ++k2) {
      bf16x8 ap = lds8(&P2w[m16 * 68 + k2 * 32 + quad * 8]);
#pragma unroll
      for (int nt2 = 0; nt2 < 2; ++nt2) {
        bf16x8 bv = lds8(&AVt[(nt2 * 16 + m16) * 68 + k2 * 32 + quad * 8]);
        oacc[nt2] = __builtin_amdgcn_mfma_f32_16x16x32_bf16(ap, bv, oacc[nt2], 0, 0, 0);
      }
    }
#pragma unroll
    for (int nt2 = 0; nt2 < 2; ++nt2)
#pragma unroll
      for (int r = 0; r < 4; ++r) {
        int token = mt * 16 + quad * 4 + r;
        if (token < 196) {
          int ch = nt2 * 16 + m16;
          float val = oacc[nt2][r] + bf2f(dwcs[token * 32 + ch]);
          t[((long)(b * 196 + token)) * 384 + h * 32 + ch] = f2bf(val);
        }
      }
  }
}

extern "C" void kernel_launch(void* const* d_in, const int* in_sizes, int n_in,
                              void* d_out, int out_size, void* d_ws, size_t ws_size,
                              hipStream_t stream) {
  (void)in_sizes; (void)n_in; (void)out_size; (void)ws_size;
  const float* x      = (const float*)d_in[0];
  const float* qkv_w  = (const float*)d_in[1];
  const float* proj_w = (const float*)d_in[2];
  const float* proj_b = (const float*)d_in[3];
  const float* dwc_w  = (const float*)d_in[4];
  const float* dwc_b  = (const float*)d_in[5];
  const float* an_b   = (const float*)d_in[6];
  const float* ah_b   = (const float*)d_in[7];
  const float* aw_b   = (const float*)d_in[8];
  const float* na_b   = (const float*)d_in[9];
  const float* ha_b   = (const float*)d_in[10];
  const float* wa_b   = (const float*)d_in[11];
  float* out = (float*)d_out;

  // workspace layout (bytes), ~387.5 MB total:
  char* ws = (char*)d_ws;
  u16*   qkv     = (u16*)ws;                       // 231,211,008
  u16*   t       = (u16*)(ws + 231211008);         //  77,070,336
  u16*   xb      = (u16*)(ws + 308281344);         //  77,070,336
  u16*   wqkvb   = (u16*)(ws + 385351680);         //     884,736
  u16*   wprojb  = (u16*)(ws + 386236416);         //     294,912
  float* bias1   = (float*)(ws + 386531328);       //     460,992
  float* bias2   = (float*)(ws + 386992320);       //     460,992

  k_bias1<<<451, 256, 0, stream>>>(an_b, ah_b, aw_b, bias1);
  k_bias2<<<451, 256, 0, stream>>>(na_b, ha_b, wa_b, bias2);
  k_f2bf<<<18816, 256, 0, stream>>>(x, xb, (long)100352 * 384);
  k_f2bf<<<216, 256, 0, stream>>>(qkv_w, wqkvb, (long)1152 * 384);
  k_f2bf<<<72, 256, 0, stream>>>(proj_w, wprojb, (long)384 * 384);
  k_mfma_qkv<<<dim3(9, 784), 256, 0, stream>>>(xb, wqkvb, qkv);
  k_fused<<<6144, 256, 0, stream>>>(qkv, bias1, bias2, dwc_w, dwc_b, t);
  k_mfma_out<<<dim3(3, 784), 256, 0, stream>>>(t, wprojb, proj_b, out);
}

// Round 4
// 728.469 us; speedup vs baseline: 1.3622x; 1.0983x over previous
//
#include <hip/hip_runtime.h>

typedef unsigned short u16;
typedef unsigned int   u32;

// B=512 N=196 C=384 H=12 D=32 A=49 W=14, 3C=1152
#define SCALE 0.17677669529663687f

using bf16x8 = __attribute__((ext_vector_type(8))) __bf16;
using f32x4  = __attribute__((ext_vector_type(4))) float;

__device__ __forceinline__ float bf2f(u16 u) {
  union { u32 i; float f; } c; c.i = ((u32)u) << 16; return c.f;
}
__device__ __forceinline__ u16 f2bf(float f) {
  union { float f; u32 i; } c; c.f = f;
  u32 x = c.i;
  return (u16)((x + 0x7fffu + ((x >> 16) & 1u)) >> 16);
}

// async global->LDS, 16B per lane (GEMM staging)
__device__ __forceinline__ void gl_lds16(const void* g, void* l) {
  __builtin_amdgcn_global_load_lds(
      (__attribute__((address_space(1))) void*)(uintptr_t)g,
      (__attribute__((address_space(3))) void*)(uintptr_t)l, 16, 0, 0);
}

// 16B LDS fragment load via two 8B reads (rows are 8B- but not 16B-aligned)
__device__ __forceinline__ bf16x8 lds8(const u16* p) {
  union { bf16x8 v; uint2 u[2]; } r;
  r.u[0] = *(const uint2*)p;
  r.u[1] = *(const uint2*)(p + 4);
  return r.v;
}

// ---------------- bias precompute (bf16 out, swapped layouts) ----------------
__device__ __forceinline__ void lin_w(int i, int& i0, int& i1, float& w0, float& w1) {
  if (i == 0)       { i0 = 0; i1 = 0; w0 = 1.f;  w1 = 0.f;  }
  else if (i == 13) { i0 = 6; i1 = 6; w0 = 1.f;  w1 = 0.f;  }
  else if (i & 1)   { int j = i >> 1; i0 = j;     i1 = j + 1; w0 = 0.75f; w1 = 0.25f; }
  else              { int j = i >> 1; i0 = j - 1; i1 = j;     w0 = 0.25f; w1 = 0.75f; }
}

// bias1 -> b1t[h][n=196][a=52 pad] bf16 (token-major so BC loads 4 agents/uint2)
__global__ void k_bias1(const float* __restrict__ an, const float* __restrict__ ah,
                        const float* __restrict__ aw, u16* __restrict__ out) {
  int idx = blockIdx.x * 256 + threadIdx.x;
  if (idx >= 12 * 196 * 52) return;
  int a = idx % 52; int n = (idx / 52) % 196; int h = idx / (52 * 196);
  u16 res = 0;
  if (a < 49) {
    int y = n / 14, x = n % 14;
    int y0, y1, x0, x1; float wy0, wy1, wx0, wx1;
    lin_w(y, y0, y1, wy0, wy1); lin_w(x, x0, x1, wx0, wx1);
    const float* p = an + (h * 49 + a) * 49;
    float v = wy0 * (wx0 * p[y0 * 7 + x0] + wx1 * p[y0 * 7 + x1])
            + wy1 * (wx0 * p[y1 * 7 + x0] + wx1 * p[y1 * 7 + x1]);
    v += ah[(h * 49 + a) * 14 + y] + aw[(h * 49 + a) * 14 + x];
    res = f2bf(v);
  }
  out[idx] = res;
}

// bias2 -> b2t[h][a=49][n=196] bf16 (agent-major so D loads 4 tokens/uint2)
__global__ void k_bias2(const float* __restrict__ na, const float* __restrict__ ha,
                        const float* __restrict__ wa, u16* __restrict__ out) {
  int idx = blockIdx.x * 256 + threadIdx.x;
  if (idx >= 12 * 49 * 196) return;
  int n = idx % 196; int a = (idx / 196) % 49; int h = idx / (196 * 49);
  int y = n / 14, x = n % 14;
  int y0, y1, x0, x1; float wy0, wy1, wx0, wx1;
  lin_w(y, y0, y1, wy0, wy1); lin_w(x, x0, x1, wx0, wx1);
  const float* p = na + (h * 49 + a) * 49;
  float v = wy0 * (wx0 * p[y0 * 7 + x0] + wx1 * p[y0 * 7 + x1])
          + wy1 * (wx0 * p[y1 * 7 + x0] + wx1 * p[y1 * 7 + x1]);
  v += ha[(h * 14 + y) * 49 + a] + wa[(h * 14 + x) * 49 + a];
  out[idx] = f2bf(v);
}

// ---------------- fp32 -> bf16 conversion ----------------
__global__ void k_f2bf(const float* __restrict__ src, u16* __restrict__ dst, long n) {
  long i = ((long)blockIdx.x * 256 + threadIdx.x) * 8;
  if (i >= n) return;
  float4 a = *(const float4*)(src + i);
  float4 b = *(const float4*)(src + i + 4);
  union { u16 s[8]; uint4 v; } pk;
  pk.s[0] = f2bf(a.x); pk.s[1] = f2bf(a.y); pk.s[2] = f2bf(a.z); pk.s[3] = f2bf(a.w);
  pk.s[4] = f2bf(b.x); pk.s[5] = f2bf(b.y); pk.s[6] = f2bf(b.z); pk.s[7] = f2bf(b.w);
  *(uint4*)(dst + i) = pk.v;
}

// ---------------- MFMA GEMM: qkv = xb @ wqkv^T (bf16 out) ----------------
// 1D grid 7056 = 8 XCDs x 882; bijective chunk swizzle: each XCD owns 98
// consecutive row-tiles so all 9 col-blocks of a row hit the same L2.
__global__ __launch_bounds__(256) void k_mfma_qkv(const u16* __restrict__ A,
    const u16* __restrict__ Bw, u16* __restrict__ out) {
  __shared__ __align__(16) u16 As[128 * 64];
  __shared__ __align__(16) u16 Bs[128 * 64];
  const int orig = blockIdx.x;
  const int wg = (orig & 7) * 882 + (orig >> 3);
  const long row0 = (long)(wg / 9) * 128;
  const int col0 = (wg % 9) * 128;
  const int tid = threadIdx.x;
  const int lane = tid & 63, w = tid >> 6;
  const int wm = (w >> 1) * 64, wn = (w & 1) * 64;
  const int quad = lane >> 4, m16 = lane & 15;
  f32x4 acc[4][4] = {};
  for (int kt = 0; kt < 6; ++kt) {
    const int k0 = kt * 64;
    __syncthreads();
#pragma unroll
    for (int i = 0; i < 4; ++i) {
      int c = i * 256 + w * 64 + lane;
      const u16* ga = A + (row0 + (c >> 3)) * 384 + k0 + (c & 7) * 8;
      gl_lds16(ga, &As[(i * 256 + w * 64) * 8]);
      const u16* gb = Bw + (long)(col0 + (c >> 3)) * 384 + k0 + (c & 7) * 8;
      gl_lds16(gb, &Bs[(i * 256 + w * 64) * 8]);
    }
    __syncthreads();
#pragma unroll
    for (int kk = 0; kk < 2; ++kk) {
      bf16x8 av[4], bv[4];
#pragma unroll
      for (int i = 0; i < 4; ++i)
        av[i] = *(const bf16x8*)&As[(wm + i * 16 + m16) * 64 + kk * 32 + quad * 8];
#pragma unroll
      for (int j = 0; j < 4; ++j)
        bv[j] = *(const bf16x8*)&Bs[(wn + j * 16 + m16) * 64 + kk * 32 + quad * 8];
#pragma unroll
      for (int i = 0; i < 4; ++i)
#pragma unroll
        for (int j = 0; j < 4; ++j)
          acc[i][j] = __builtin_amdgcn_mfma_f32_16x16x32_bf16(av[i], bv[j], acc[i][j], 0, 0, 0);
    }
  }
#pragma unroll
  for (int i = 0; i < 4; ++i)
#pragma unroll
    for (int r = 0; r < 4; ++r) {
      long row = row0 + wm + i * 16 + quad * 4 + r;
      u16* op = out + row * 1152 + col0 + wn + m16;
#pragma unroll
      for (int j = 0; j < 4; ++j) op[j * 16] = f2bf(acc[i][j][r]);
    }
}

// ---------------- MFMA GEMM: out = t @ proj^T + pb (fp32 out) ----------------
// 1D grid 2352 = 8 x 294, same swizzle.
__global__ __launch_bounds__(256) void k_mfma_out(const u16* __restrict__ A,
    const u16* __restrict__ Bw, const float* __restrict__ pb, float* __restrict__ out) {
  __shared__ __align__(16) u16 As[128 * 64];
  __shared__ __align__(16) u16 Bs[128 * 64];
  const int orig = blockIdx.x;
  const int wg = (orig & 7) * 294 + (orig >> 3);
  const long row0 = (long)(wg / 3) * 128;
  const int col0 = (wg % 3) * 128;
  const int tid = threadIdx.x;
  const int lane = tid & 63, w = tid >> 6;
  const int wm = (w >> 1) * 64, wn = (w & 1) * 64;
  const int quad = lane >> 4, m16 = lane & 15;
  f32x4 acc[4][4] = {};
  for (int kt = 0; kt < 6; ++kt) {
    const int k0 = kt * 64;
    __syncthreads();
#pragma unroll
    for (int i = 0; i < 4; ++i) {
      int c = i * 256 + w * 64 + lane;
      const u16* ga = A + (row0 + (c >> 3)) * 384 + k0 + (c & 7) * 8;
      gl_lds16(ga, &As[(i * 256 + w * 64) * 8]);
      const u16* gb = Bw + (long)(col0 + (c >> 3)) * 384 + k0 + (c & 7) * 8;
      gl_lds16(gb, &Bs[(i * 256 + w * 64) * 8]);
    }
    __syncthreads();
#pragma unroll
    for (int kk = 0; kk < 2; ++kk) {
      bf16x8 av[4], bv[4];
#pragma unroll
      for (int i = 0; i < 4; ++i)
        av[i] = *(const bf16x8*)&As[(wm + i * 16 + m16) * 64 + kk * 32 + quad * 8];
#pragma unroll
      for (int j = 0; j < 4; ++j)
        bv[j] = *(const bf16x8*)&Bs[(wn + j * 16 + m16) * 64 + kk * 32 + quad * 8];
#pragma unroll
      for (int i = 0; i < 4; ++i)
#pragma unroll
        for (int j = 0; j < 4; ++j)
          acc[i][j] = __builtin_amdgcn_mfma_f32_16x16x32_bf16(av[i], bv[j], acc[i][j], 0, 0, 0);
    }
  }
  float pbv[4];
#pragma unroll
  for (int j = 0; j < 4; ++j) pbv[j] = pb[col0 + wn + j * 16 + m16];
#pragma unroll
  for (int i = 0; i < 4; ++i)
#pragma unroll
    for (int r = 0; r < 4; ++r) {
      long row = row0 + wm + i * 16 + quad * 4 + r;
      float* op = out + row * 384 + col0 + wn + m16;
#pragma unroll
      for (int j = 0; j < 4; ++j) op[j * 16] = acc[i][j][r] + pbv[j];
    }
}

// ---------------- fused pool + agent-attn + q-attn + dwc ----------------
// block = (b,h), 256 threads (4 waves). LDS = 38784 B -> 4 blocks/CU (16 waves).
// This rev: V stored TRANSPOSED (Vt[32ch][204 tok pitch]) so BC's MFMA
// B-fragment is one vector lds8 (was 8x ds_read_u16); dwc reworked on even
// token-pairs with aligned u32 reads; biases are bf16 with layouts matching
// the lane->element maps so BC loads 4 agents/uint2 and D loads 4 tokens/uint2.
// Liveness:  scr  (BC, per-wave)        @0      4608
//            dwcs (C2 -> E)             @4608   12544
//            AVt  (end-BC -> E)         @17152  4352
//            Vt   (A -> C2)             @21504  13056
//            P2w  (D/E, per-wave)       @21504  8704 (over dead Vt)
//            ags  (A -> D, 49 rows)     @34560  3528
//            dwcw (A -> C2)             @38088  640
#define OFF_SCR   0
#define OFF_DWCS  4608
#define OFF_AVT   17152
#define OFF_VT    21504
#define OFF_P2    21504
#define OFF_AGS   34560
#define OFF_DWCW  38088
#define SMEM_BYTES 38784
#define VT_PITCH  204

__global__ __launch_bounds__(256, 4) void k_fused(const u16* __restrict__ qkv,
    const u16* __restrict__ b1t, const u16* __restrict__ b2t,
    const float* __restrict__ dwc_w, const float* __restrict__ dwc_b,
    u16* __restrict__ t) {
  __shared__ __align__(16) char smem[SMEM_BYTES];
  u16* AVt  = (u16*)(smem + OFF_AVT);
  u16* dwcs = (u16*)(smem + OFF_DWCS);
  u16* Vt   = (u16*)(smem + OFF_VT);
  u16* ags  = (u16*)(smem + OFF_AGS);
  u16* dwcw = (u16*)(smem + OFF_DWCW);

  const int orig = blockIdx.x;
  const int bh = (orig & 7) * 768 + (orig >> 3);   // XCD chunk swizzle (6144=8x768)
  const int b = bh / 12, h = bh % 12;
  const int tid = threadIdx.x;
  const int lane = tid & 63, w = tid >> 6;
  const int quad = lane >> 4, m16 = lane & 15;
  u16* scr = (u16*)(smem + OFF_SCR) + w * 576;    // [16][36] u16 per wave
  u16* P2w = (u16*)(smem + OFF_P2)  + w * 1088;   // [16][68] u16 per wave
  const long qkvb = (long)b * 196 * 1152;
  const f32x4 zf = {0.f, 0.f, 0.f, 0.f};

  // ===== Phase A: stage V transposed, dwc weights, pooled agents =====
  if (tid < 196) {
    const uint2* v2p = (const uint2*)(qkv + qkvb + (long)tid * 1152 + 768 + h * 32);
    u32 vv[16];
#pragma unroll
    for (int i = 0; i < 8; ++i) { uint2 d = v2p[i]; vv[2 * i] = d.x; vv[2 * i + 1] = d.y; }
#pragma unroll
    for (int i = 0; i < 16; ++i) {
      Vt[(2 * i) * VT_PITCH + tid]     = (u16)(vv[i] & 0xffff);
      Vt[(2 * i + 1) * VT_PITCH + tid] = (u16)(vv[i] >> 16);
    }
  }
  // zero pad tokens 196..203 (BC's lds8 tails read them; must be finite)
  { int ch = tid >> 3, tk = 196 + (tid & 7); Vt[ch * VT_PITCH + tk] = 0; }
  for (int i = tid; i < 320; i += 256) {
    int tap = i >> 5, ch = i & 31;
    float v = (tap < 9) ? dwc_w[(h * 32 + ch) * 9 + tap] : dwc_b[h * 32 + ch];
    dwcw[tap * 32 + ch] = f2bf(v);
  }
  for (int i = tid; i < 784; i += 256) {  // 49 agents x 16 ch-pairs
    int a = i >> 4, cp = i & 15;
    int ay = a / 7, ax = a % 7;
    int y0 = ay * 2, x0 = ax * 2;
    const u16* q0 = qkv + qkvb + h * 32 + cp * 2;
    u32 v00 = *(const u32*)(q0 + (long)(y0 * 14 + x0) * 1152);
    u32 v01 = *(const u32*)(q0 + (long)(y0 * 14 + x0 + 1) * 1152);
    u32 v10 = *(const u32*)(q0 + (long)((y0 + 1) * 14 + x0) * 1152);
    u32 v11 = *(const u32*)(q0 + (long)((y0 + 1) * 14 + x0 + 1) * 1152);
    float lo = 0.25f * (bf2f((u16)(v00 & 0xffff)) + bf2f((u16)(v01 & 0xffff))
                      + bf2f((u16)(v10 & 0xffff)) + bf2f((u16)(v11 & 0xffff)));
    float hi = 0.25f * (bf2f((u16)(v00 >> 16)) + bf2f((u16)(v01 >> 16))
                      + bf2f((u16)(v10 >> 16)) + bf2f((u16)(v11 >> 16)));
    *(u32*)&ags[a * 36 + cp * 2] = (u32)f2bf(lo) | ((u32)f2bf(hi) << 16);
  }
  __syncthreads();

  // ===== Phase BC: fused S1-softmax-numerator + AV accumulate =====
  {
    int ar = 16 * w + m16; if (ar > 48) ar = 48;   // clamped: dup rows masked later
    bf16x8 av = lds8(&ags[ar * 36 + quad * 8]);
    const u16* kq = qkv + qkvb + 384 + h * 32 + quad * 8;
    const u16* b1 = b1t + (long)h * 196 * 52;
    f32x4 avacc[2] = {zf, zf};
    float rs[4] = {0.f, 0.f, 0.f, 0.f};
    for (int k7 = 0; k7 < 7; ++k7) {
#pragma unroll
      for (int t2 = 0; t2 < 2; ++t2) {
        int nt = k7 * 2 + t2;
        if (nt < 13) {
          int token = nt * 16 + m16;               // <= 207 (b1t padded)
          int tk = token; if (tk > 195) tk = 195;
          bf16x8 bv = *(const bf16x8*)(kq + (long)tk * 1152);
          f32x4 s = __builtin_amdgcn_mfma_f32_16x16x32_bf16(av, bv, zf, 0, 0, 0);
          union { uint2 v; u16 s4[4]; } bb;
          bb.v = *(const uint2*)(b1 + token * 52 + 16 * w + quad * 4);
#pragma unroll
          for (int r = 0; r < 4; ++r) {
            int agent = 16 * w + quad * 4 + r;
            float e = 0.f;
            if (agent < 49 && token < 196)
              e = __expf(s[r] * SCALE + bf2f(bb.s4[r]));
            rs[r] += e;
            scr[(quad * 4 + r) * 36 + t2 * 16 + m16] = f2bf(e);
          }
        } else {
#pragma unroll
          for (int r = 0; r < 4; ++r)
            scr[(quad * 4 + r) * 36 + t2 * 16 + m16] = 0;
        }
      }
      bf16x8 ap = lds8(&scr[m16 * 36 + quad * 8]);
#pragma unroll
      for (int ntc = 0; ntc < 2; ++ntc) {
        bf16x8 bvv = lds8(&Vt[(ntc * 16 + m16) * VT_PITCH + k7 * 32 + quad * 8]);
        avacc[ntc] = __builtin_amdgcn_mfma_f32_16x16x32_bf16(ap, bvv, avacc[ntc], 0, 0, 0);
      }
    }
    float inv[4];
#pragma unroll
    for (int r = 0; r < 4; ++r) {
      rs[r] += __shfl_xor(rs[r], 1);
      rs[r] += __shfl_xor(rs[r], 2);
      rs[r] += __shfl_xor(rs[r], 4);
      rs[r] += __shfl_xor(rs[r], 8);
      // padding agents (>=49) have rs==0; force inv=0 so AVt cols stay 0 (not NaN)
      inv[r] = (16 * w + quad * 4 + r < 49) ? 1.f / rs[r] : 0.f;
    }
#pragma unroll
    for (int ntc = 0; ntc < 2; ++ntc)
#pragma unroll
      for (int r = 0; r < 4; ++r)
        AVt[(ntc * 16 + m16) * 68 + 16 * w + quad * 4 + r] = f2bf(avacc[ntc][r] * inv[r]);
  }

  // ===== Phase C2: depthwise 3x3 from Vt -> dwcs (thread = ch x slot8, even pairs) =====
  {
    int ch = tid & 31, slot = tid >> 5;
    const u16* Vr = &Vt[ch * VT_PITCH];
    float wv[10];
#pragma unroll
    for (int tp = 0; tp < 10; ++tp) wv[tp] = bf2f(dwcw[tp * 32 + ch]);
    for (int p = slot; p < 98; p += 8) {
      int t0 = 2 * p;
      int y = t0 / 14, x0 = t0 % 14;               // x0 even
      float a0 = wv[9], a1 = wv[9];                // conv bias
#pragma unroll
      for (int dy = -1; dy <= 1; ++dy) {
        int yy = y + dy;
        if (yy < 0 || yy > 13) continue;
        int tb = yy * 14 + x0;
        float wl = wv[(dy + 1) * 3], wc = wv[(dy + 1) * 3 + 1], wr = wv[(dy + 1) * 3 + 2];
        u32 vm = *(const u32*)(Vr + tb);
        float vx0 = bf2f((u16)(vm & 0xffff)), vx1 = bf2f((u16)(vm >> 16));
        float vxm1 = 0.f, vx2 = 0.f;
        if (x0 > 0)  { u32 vl = *(const u32*)(Vr + tb - 2); vxm1 = bf2f((u16)(vl >> 16)); }
        if (x0 < 12) { u32 vr2 = *(const u32*)(Vr + tb + 2); vx2 = bf2f((u16)(vr2 & 0xffff)); }
        a0 += wl * vxm1 + wc * vx0 + wr * vx1;
        a1 += wl * vx0  + wc * vx1 + wr * vx2;
      }
      dwcs[t0 * 32 + ch]       = f2bf(a0);
      dwcs[(t0 + 1) * 32 + ch] = f2bf(a1);
    }
  }
  __syncthreads();  // AVt/dwcs ready for all waves; Vt dead -> P2w region usable

  // ===== Phase D+E: per m-tile: S2 softmax -> P2w -> Out = P2 @ AV (+dwc) -> t =====
  const u16* b2 = b2t + (long)h * 49 * 196;
  for (int mt = w; mt < 13; mt += 4) {
    int tka = mt * 16 + m16; if (tka > 195) tka = 195;
    bf16x8 aq = *(const bf16x8*)(qkv + qkvb + (long)tka * 1152 + h * 32 + quad * 8);
    f32x4 sacc[4];
#pragma unroll
    for (int nt = 0; nt < 4; ++nt) {
      int gr = nt * 16 + m16; if (gr > 48) gr = 48;   // clamped dup, masked below
      bf16x8 bv = lds8(&ags[gr * 36 + quad * 8]);
      sacc[nt] = __builtin_amdgcn_mfma_f32_16x16x32_bf16(aq, bv, zf, 0, 0, 0);
    }
    int tb = mt * 16 + quad * 4; if (tb > 192) tb = 192;  // keep loads in-row, finite
    float rs[4] = {0.f, 0.f, 0.f, 0.f};
#pragma unroll
    for (int nt = 0; nt < 4; ++nt) {
      int agent = nt * 16 + m16;
      union { uint2 v; u16 s4[4]; } bb;
      bb.v = *(const uint2*)(b2 + agent * 196 + tb);     // b2t padded for agent>=49
#pragma unroll
      for (int r = 0; r < 4; ++r) {
        float e = 0.f;
        if (agent < 49)
          e = __expf(sacc[nt][r] * SCALE + bf2f(bb.s4[r]));
        sacc[nt][r] = e;
        rs[r] += e;
      }
    }
    float inv[4];
#pragma unroll
    for (int r = 0; r < 4; ++r) {
      rs[r] += __shfl_xor(rs[r], 1);
      rs[r] += __shfl_xor(rs[r], 2);
      rs[r] += __shfl_xor(rs[r], 4);
      rs[r] += __shfl_xor(rs[r], 8);
      inv[r] = 1.f / rs[r];
    }
#pragma unroll
    for (int nt = 0; nt < 4; ++nt)
#pragma unroll
      for (int r = 0; r < 4; ++r)
        P2w[(quad * 4 + r) * 68 + nt * 16 + m16] = f2bf(sacc[nt][r] * inv[r]);
    // Out = P2 @ AV  (same-wave LDS write->read: DS is in-order per wave)
    f32x4 oacc[2] = {zf, zf};
#pragma unroll
    for (int k2 = 0; k2 < 2; ++k2) {
      bf16x8 ap = lds8(&P2w[m16 * 68 + k2 * 32 + quad * 8]);
#pragma unroll
      for (int nt2 = 0; nt2 < 2; ++nt2) {
        bf16x8 bv = lds8(&AVt[(nt2 * 16 + m16) * 68 + k2 * 32 + quad * 8]);
        oacc[nt2] = __builtin_amdgcn_mfma_f32_16x16x32_bf16(ap, bv, oacc[nt2], 0, 0, 0);
      }
    }
#pragma unroll
    for (int nt2 = 0; nt2 < 2; ++nt2)
#pragma unroll
      for (int r = 0; r < 4; ++r) {
        int token = mt * 16 + quad * 4 + r;
        if (token < 196) {
          int ch = nt2 * 16 + m16;
          float val = oacc[nt2][r] + bf2f(dwcs[token * 32 + ch]);
          t[((long)(b * 196 + token)) * 384 + h * 32 + ch] = f2bf(val);
        }
      }
  }
}

extern "C" void kernel_launch(void* const* d_in, const int* in_sizes, int n_in,
                              void* d_out, int out_size, void* d_ws, size_t ws_size,
                              hipStream_t stream) {
  (void)in_sizes; (void)n_in; (void)out_size; (void)ws_size;
  const float* x      = (const float*)d_in[0];
  const float* qkv_w  = (const float*)d_in[1];
  const float* proj_w = (const float*)d_in[2];
  const float* proj_b = (const float*)d_in[3];
  const float* dwc_w  = (const float*)d_in[4];
  const float* dwc_b  = (const float*)d_in[5];
  const float* an_b   = (const float*)d_in[6];
  const float* ah_b   = (const float*)d_in[7];
  const float* aw_b   = (const float*)d_in[8];
  const float* na_b   = (const float*)d_in[9];
  const float* ha_b   = (const float*)d_in[10];
  const float* wa_b   = (const float*)d_in[11];
  float* out = (float*)d_out;

  // workspace layout (bytes), ~387.0 MB total (under previous 387.45 MB):
  char* ws = (char*)d_ws;
  u16*   qkv     = (u16*)ws;                       // 231,211,008
  u16*   t       = (u16*)(ws + 231211008);         //  77,070,336
  u16*   xb      = (u16*)(ws + 308281344);         //  77,070,336
  u16*   wqkvb   = (u16*)(ws + 385351680);         //     884,736
  u16*   wprojb  = (u16*)(ws + 386236416);         //     294,912
  u16*   b1t     = (u16*)(ws + 386531328);         //     244,608 + 1,408 pad
  u16*   b2t     = (u16*)(ws + 386777344);         //     230,496 + 6,144 pad

  k_bias1<<<478, 256, 0, stream>>>(an_b, ah_b, aw_b, b1t);
  k_bias2<<<451, 256, 0, stream>>>(na_b, ha_b, wa_b, b2t);
  k_f2bf<<<18816, 256, 0, stream>>>(x, xb, (long)100352 * 384);
  k_f2bf<<<216, 256, 0, stream>>>(qkv_w, wqkvb, (long)1152 * 384);
  k_f2bf<<<72, 256, 0, stream>>>(proj_w, wprojb, (long)384 * 384);
  k_mfma_qkv<<<7056, 256, 0, stream>>>(xb, wqkvb, qkv);
  k_fused<<<6144, 256, 0, stream>>>(qkv, b1t, b2t, dwc_w, dwc_b, t);
  k_mfma_out<<<2352, 256, 0, stream>>>(t, wprojb, proj_b, out);
}

// Round 5
// 716.943 us; speedup vs baseline: 1.3841x; 1.0161x over previous
//
#include <hip/hip_runtime.h>

typedef unsigned short u16;
typedef unsigned int   u32;

// B=512 N=196 C=384 H=12 D=32 A=49 W=14, 3C=1152
#define SCALE 0.17677669529663687f

using bf16x8 = __attribute__((ext_vector_type(8))) __bf16;
using f32x4  = __attribute__((ext_vector_type(4))) float;

__device__ __forceinline__ float bf2f(u16 u) {
  union { u32 i; float f; } c; c.i = ((u32)u) << 16; return c.f;
}
// native cast -> compiler emits hardware v_cvt_pk_bf16_f32 (RNE), ~5x fewer
// VALU ops than the old bit-twiddled round-to-nearest-even
__device__ __forceinline__ u16 f2bf(float f) {
  union { __bf16 b; u16 u; } c; c.b = (__bf16)f; return c.u;
}

// async global->LDS, 16B per lane (GEMM staging)
__device__ __forceinline__ void gl_lds16(const void* g, void* l) {
  __builtin_amdgcn_global_load_lds(
      (__attribute__((address_space(1))) void*)(uintptr_t)g,
      (__attribute__((address_space(3))) void*)(uintptr_t)l, 16, 0, 0);
}

// 16B LDS fragment load via two 8B reads (rows are 8B- but not 16B-aligned)
__device__ __forceinline__ bf16x8 lds8(const u16* p) {
  union { bf16x8 v; uint2 u[2]; } r;
  r.u[0] = *(const uint2*)p;
  r.u[1] = *(const uint2*)(p + 4);
  return r.v;
}

// ---------------- bias precompute (bf16 out, swapped layouts) ----------------
__device__ __forceinline__ void lin_w(int i, int& i0, int& i1, float& w0, float& w1) {
  if (i == 0)       { i0 = 0; i1 = 0; w0 = 1.f;  w1 = 0.f;  }
  else if (i == 13) { i0 = 6; i1 = 6; w0 = 1.f;  w1 = 0.f;  }
  else if (i & 1)   { int j = i >> 1; i0 = j;     i1 = j + 1; w0 = 0.75f; w1 = 0.25f; }
  else              { int j = i >> 1; i0 = j - 1; i1 = j;     w0 = 0.25f; w1 = 0.75f; }
}

// bias1 -> b1t[h][n=196][a=52 pad] bf16 (token-major so BC loads 4 agents/uint2)
__global__ void k_bias1(const float* __restrict__ an, const float* __restrict__ ah,
                        const float* __restrict__ aw, u16* __restrict__ out) {
  int idx = blockIdx.x * 256 + threadIdx.x;
  if (idx >= 12 * 196 * 52) return;
  int a = idx % 52; int n = (idx / 52) % 196; int h = idx / (52 * 196);
  u16 res = 0;
  if (a < 49) {
    int y = n / 14, x = n % 14;
    int y0, y1, x0, x1; float wy0, wy1, wx0, wx1;
    lin_w(y, y0, y1, wy0, wy1); lin_w(x, x0, x1, wx0, wx1);
    const float* p = an + (h * 49 + a) * 49;
    float v = wy0 * (wx0 * p[y0 * 7 + x0] + wx1 * p[y0 * 7 + x1])
            + wy1 * (wx0 * p[y1 * 7 + x0] + wx1 * p[y1 * 7 + x1]);
    v += ah[(h * 49 + a) * 14 + y] + aw[(h * 49 + a) * 14 + x];
    res = f2bf(v);
  }
  out[idx] = res;
}

// bias2 -> b2t[h][a=49][n=196] bf16 (agent-major so D loads 4 tokens/uint2)
__global__ void k_bias2(const float* __restrict__ na, const float* __restrict__ ha,
                        const float* __restrict__ wa, u16* __restrict__ out) {
  int idx = blockIdx.x * 256 + threadIdx.x;
  if (idx >= 12 * 49 * 196) return;
  int n = idx % 196; int a = (idx / 196) % 49; int h = idx / (196 * 49);
  int y = n / 14, x = n % 14;
  int y0, y1, x0, x1; float wy0, wy1, wx0, wx1;
  lin_w(y, y0, y1, wy0, wy1); lin_w(x, x0, x1, wx0, wx1);
  const float* p = na + (h * 49 + a) * 49;
  float v = wy0 * (wx0 * p[y0 * 7 + x0] + wx1 * p[y0 * 7 + x1])
          + wy1 * (wx0 * p[y1 * 7 + x0] + wx1 * p[y1 * 7 + x1]);
  v += ha[(h * 14 + y) * 49 + a] + wa[(h * 14 + x) * 49 + a];
  out[idx] = f2bf(v);
}

// ---------------- fp32 -> bf16 conversion (weights only now) ----------------
__global__ void k_f2bf(const float* __restrict__ src, u16* __restrict__ dst, long n) {
  long i = ((long)blockIdx.x * 256 + threadIdx.x) * 8;
  if (i >= n) return;
  float4 a = *(const float4*)(src + i);
  float4 b = *(const float4*)(src + i + 4);
  union { u16 s[8]; uint4 v; } pk;
  pk.s[0] = f2bf(a.x); pk.s[1] = f2bf(a.y); pk.s[2] = f2bf(a.z); pk.s[3] = f2bf(a.w);
  pk.s[4] = f2bf(b.x); pk.s[5] = f2bf(b.y); pk.s[6] = f2bf(b.z); pk.s[7] = f2bf(b.w);
  *(uint4*)(dst + i) = pk.v;
}

// ---------------- MFMA GEMM: qkv = x(fp32) @ wqkv^T (bf16 out) ----------------
// A-side: fp32 loaded to regs EARLY (before barrier, hides under prev compute),
// converted to bf16 in-reg (hw cvt_pk), ds_write_b128 — fuses the old k_f2bf(x)
// pass (231 MB HBM round-trip) into staging. B-side keeps global_load_lds.
// 1D grid 7056 = 8 XCDs x 882; bijective chunk swizzle.
__global__ __launch_bounds__(256) void k_mfma_qkv(const float* __restrict__ X,
    const u16* __restrict__ Bw, u16* __restrict__ out) {
  __shared__ __align__(16) u16 As[128 * 64];
  __shared__ __align__(16) u16 Bs[128 * 64];
  const int orig = blockIdx.x;
  const int wg = (orig & 7) * 882 + (orig >> 3);
  const long row0 = (long)(wg / 9) * 128;
  const int col0 = (wg % 9) * 128;
  const int tid = threadIdx.x;
  const int lane = tid & 63, w = tid >> 6;
  const int wm = (w >> 1) * 64, wn = (w & 1) * 64;
  const int quad = lane >> 4, m16 = lane & 15;
  f32x4 acc[4][4] = {};
  for (int kt = 0; kt < 6; ++kt) {
    const int k0 = kt * 64;
    // issue fp32 A loads before the barrier (latency hides under prev compute)
    float4 a0[4], a1[4];
#pragma unroll
    for (int i = 0; i < 4; ++i) {
      int c = i * 256 + w * 64 + lane;
      const float* gx = X + (row0 + (c >> 3)) * 384 + k0 + (c & 7) * 8;
      a0[i] = *(const float4*)gx;
      a1[i] = *(const float4*)(gx + 4);
    }
    __syncthreads();
#pragma unroll
    for (int i = 0; i < 4; ++i) {
      int c = i * 256 + w * 64 + lane;
      const u16* gb = Bw + (long)(col0 + (c >> 3)) * 384 + k0 + (c & 7) * 8;
      gl_lds16(gb, &Bs[(i * 256 + w * 64) * 8]);
      union { u16 s[8]; uint4 v; } pk;
      pk.s[0] = f2bf(a0[i].x); pk.s[1] = f2bf(a0[i].y);
      pk.s[2] = f2bf(a0[i].z); pk.s[3] = f2bf(a0[i].w);
      pk.s[4] = f2bf(a1[i].x); pk.s[5] = f2bf(a1[i].y);
      pk.s[6] = f2bf(a1[i].z); pk.s[7] = f2bf(a1[i].w);
      *(uint4*)&As[(long)c * 8] = pk.v;
    }
    __syncthreads();
#pragma unroll
    for (int kk = 0; kk < 2; ++kk) {
      bf16x8 av[4], bv[4];
#pragma unroll
      for (int i = 0; i < 4; ++i)
        av[i] = *(const bf16x8*)&As[(wm + i * 16 + m16) * 64 + kk * 32 + quad * 8];
#pragma unroll
      for (int j = 0; j < 4; ++j)
        bv[j] = *(const bf16x8*)&Bs[(wn + j * 16 + m16) * 64 + kk * 32 + quad * 8];
#pragma unroll
      for (int i = 0; i < 4; ++i)
#pragma unroll
        for (int j = 0; j < 4; ++j)
          acc[i][j] = __builtin_amdgcn_mfma_f32_16x16x32_bf16(av[i], bv[j], acc[i][j], 0, 0, 0);
    }
  }
#pragma unroll
  for (int i = 0; i < 4; ++i)
#pragma unroll
    for (int r = 0; r < 4; ++r) {
      long row = row0 + wm + i * 16 + quad * 4 + r;
      u16* op = out + row * 1152 + col0 + wn + m16;
#pragma unroll
      for (int j = 0; j < 4; ++j) op[j * 16] = f2bf(acc[i][j][r]);
    }
}

// ---------------- MFMA GEMM: out = t @ proj^T + pb (fp32 out) ----------------
// 1D grid 2352 = 8 x 294, same swizzle.
__global__ __launch_bounds__(256) void k_mfma_out(const u16* __restrict__ A,
    const u16* __restrict__ Bw, const float* __restrict__ pb, float* __restrict__ out) {
  __shared__ __align__(16) u16 As[128 * 64];
  __shared__ __align__(16) u16 Bs[128 * 64];
  const int orig = blockIdx.x;
  const int wg = (orig & 7) * 294 + (orig >> 3);
  const long row0 = (long)(wg / 3) * 128;
  const int col0 = (wg % 3) * 128;
  const int tid = threadIdx.x;
  const int lane = tid & 63, w = tid >> 6;
  const int wm = (w >> 1) * 64, wn = (w & 1) * 64;
  const int quad = lane >> 4, m16 = lane & 15;
  f32x4 acc[4][4] = {};
  for (int kt = 0; kt < 6; ++kt) {
    const int k0 = kt * 64;
    __syncthreads();
#pragma unroll
    for (int i = 0; i < 4; ++i) {
      int c = i * 256 + w * 64 + lane;
      const u16* ga = A + (row0 + (c >> 3)) * 384 + k0 + (c & 7) * 8;
      gl_lds16(ga, &As[(i * 256 + w * 64) * 8]);
      const u16* gb = Bw + (long)(col0 + (c >> 3)) * 384 + k0 + (c & 7) * 8;
      gl_lds16(gb, &Bs[(i * 256 + w * 64) * 8]);
    }
    __syncthreads();
#pragma unroll
    for (int kk = 0; kk < 2; ++kk) {
      bf16x8 av[4], bv[4];
#pragma unroll
      for (int i = 0; i < 4; ++i)
        av[i] = *(const bf16x8*)&As[(wm + i * 16 + m16) * 64 + kk * 32 + quad * 8];
#pragma unroll
      for (int j = 0; j < 4; ++j)
        bv[j] = *(const bf16x8*)&Bs[(wn + j * 16 + m16) * 64 + kk * 32 + quad * 8];
#pragma unroll
      for (int i = 0; i < 4; ++i)
#pragma unroll
        for (int j = 0; j < 4; ++j)
          acc[i][j] = __builtin_amdgcn_mfma_f32_16x16x32_bf16(av[i], bv[j], acc[i][j], 0, 0, 0);
    }
  }
  float pbv[4];
#pragma unroll
  for (int j = 0; j < 4; ++j) pbv[j] = pb[col0 + wn + j * 16 + m16];
#pragma unroll
  for (int i = 0; i < 4; ++i)
#pragma unroll
    for (int r = 0; r < 4; ++r) {
      long row = row0 + wm + i * 16 + quad * 4 + r;
      float* op = out + row * 384 + col0 + wn + m16;
#pragma unroll
      for (int j = 0; j < 4; ++j) op[j * 16] = acc[i][j][r] + pbv[j];
    }
}

// ---------------- fused pool + agent-attn + q-attn + dwc ----------------
// block = (b,h), 256 threads (4 waves). LDS = 38784 B -> 4 blocks/CU (16 waves).
// Liveness:  scr  (BC, per-wave)        @0      4608
//            dwcs (C2 -> E)             @4608   12544
//            AVt  (end-BC -> E)         @17152  4352
//            Vt   (A -> C2)             @21504  13056
//            P2w  (D/E, per-wave)       @21504  8704 (over dead Vt)
//            ags  (A -> D, 49 rows)     @34560  3528
//            dwcw (A -> C2)             @38088  640
#define OFF_SCR   0
#define OFF_DWCS  4608
#define OFF_AVT   17152
#define OFF_VT    21504
#define OFF_P2    21504
#define OFF_AGS   34560
#define OFF_DWCW  38088
#define SMEM_BYTES 38784
#define VT_PITCH  204

__global__ __launch_bounds__(256, 4) void k_fused(const u16* __restrict__ qkv,
    const u16* __restrict__ b1t, const u16* __restrict__ b2t,
    const float* __restrict__ dwc_w, const float* __restrict__ dwc_b,
    u16* __restrict__ t) {
  __shared__ __align__(16) char smem[SMEM_BYTES];
  u16* AVt  = (u16*)(smem + OFF_AVT);
  u16* dwcs = (u16*)(smem + OFF_DWCS);
  u16* Vt   = (u16*)(smem + OFF_VT);
  u16* ags  = (u16*)(smem + OFF_AGS);
  u16* dwcw = (u16*)(smem + OFF_DWCW);

  const int orig = blockIdx.x;
  const int bh = (orig & 7) * 768 + (orig >> 3);   // XCD chunk swizzle (6144=8x768)
  const int b = bh / 12, h = bh % 12;
  const int tid = threadIdx.x;
  const int lane = tid & 63, w = tid >> 6;
  const int quad = lane >> 4, m16 = lane & 15;
  u16* scr = (u16*)(smem + OFF_SCR) + w * 576;    // [16][36] u16 per wave
  u16* P2w = (u16*)(smem + OFF_P2)  + w * 1088;   // [16][68] u16 per wave
  const long qkvb = (long)b * 196 * 1152;
  const f32x4 zf = {0.f, 0.f, 0.f, 0.f};

  // ===== Phase A: stage V transposed, dwc weights, pooled agents =====
  if (tid < 196) {
    const uint2* v2p = (const uint2*)(qkv + qkvb + (long)tid * 1152 + 768 + h * 32);
    u32 vv[16];
#pragma unroll
    for (int i = 0; i < 8; ++i) { uint2 d = v2p[i]; vv[2 * i] = d.x; vv[2 * i + 1] = d.y; }
#pragma unroll
    for (int i = 0; i < 16; ++i) {
      Vt[(2 * i) * VT_PITCH + tid]     = (u16)(vv[i] & 0xffff);
      Vt[(2 * i + 1) * VT_PITCH + tid] = (u16)(vv[i] >> 16);
    }
  }
  // zero pad tokens 196..203 (BC's lds8 tails read them; must be finite)
  { int ch = tid >> 3, tk = 196 + (tid & 7); Vt[ch * VT_PITCH + tk] = 0; }
  for (int i = tid; i < 320; i += 256) {
    int tap = i >> 5, ch = i & 31;
    float v = (tap < 9) ? dwc_w[(h * 32 + ch) * 9 + tap] : dwc_b[h * 32 + ch];
    dwcw[tap * 32 + ch] = f2bf(v);
  }
  for (int i = tid; i < 784; i += 256) {  // 49 agents x 16 ch-pairs
    int a = i >> 4, cp = i & 15;
    int ay = a / 7, ax = a % 7;
    int y0 = ay * 2, x0 = ax * 2;
    const u16* q0 = qkv + qkvb + h * 32 + cp * 2;
    u32 v00 = *(const u32*)(q0 + (long)(y0 * 14 + x0) * 1152);
    u32 v01 = *(const u32*)(q0 + (long)(y0 * 14 + x0 + 1) * 1152);
    u32 v10 = *(const u32*)(q0 + (long)((y0 + 1) * 14 + x0) * 1152);
    u32 v11 = *(const u32*)(q0 + (long)((y0 + 1) * 14 + x0 + 1) * 1152);
    float lo = 0.25f * (bf2f((u16)(v00 & 0xffff)) + bf2f((u16)(v01 & 0xffff))
                      + bf2f((u16)(v10 & 0xffff)) + bf2f((u16)(v11 & 0xffff)));
    float hi = 0.25f * (bf2f((u16)(v00 >> 16)) + bf2f((u16)(v01 >> 16))
                      + bf2f((u16)(v10 >> 16)) + bf2f((u16)(v11 >> 16)));
    *(u32*)&ags[a * 36 + cp * 2] = (u32)f2bf(lo) | ((u32)f2bf(hi) << 16);
  }
  __syncthreads();

  // ===== Phase BC: fused S1-softmax-numerator + AV accumulate =====
  {
    int ar = 16 * w + m16; if (ar > 48) ar = 48;   // clamped: dup rows masked later
    bf16x8 av = lds8(&ags[ar * 36 + quad * 8]);
    const u16* kq = qkv + qkvb + 384 + h * 32 + quad * 8;
    const u16* b1 = b1t + (long)h * 196 * 52;
    f32x4 avacc[2] = {zf, zf};
    float rs[4] = {0.f, 0.f, 0.f, 0.f};
    for (int k7 = 0; k7 < 7; ++k7) {
#pragma unroll
      for (int t2 = 0; t2 < 2; ++t2) {
        int nt = k7 * 2 + t2;
        if (nt < 13) {
          int token = nt * 16 + m16;               // <= 207 (b1t padded)
          int tk = token; if (tk > 195) tk = 195;
          bf16x8 bv = *(const bf16x8*)(kq + (long)tk * 1152);
          f32x4 s = __builtin_amdgcn_mfma_f32_16x16x32_bf16(av, bv, zf, 0, 0, 0);
          union { uint2 v; u16 s4[4]; } bb;
          bb.v = *(const uint2*)(b1 + token * 52 + 16 * w + quad * 4);
#pragma unroll
          for (int r = 0; r < 4; ++r) {
            int agent = 16 * w + quad * 4 + r;
            float e = 0.f;
            if (agent < 49 && token < 196)
              e = __expf(s[r] * SCALE + bf2f(bb.s4[r]));
            rs[r] += e;
            scr[(quad * 4 + r) * 36 + t2 * 16 + m16] = f2bf(e);
          }
        } else {
#pragma unroll
          for (int r = 0; r < 4; ++r)
            scr[(quad * 4 + r) * 36 + t2 * 16 + m16] = 0;
        }
      }
      bf16x8 ap = lds8(&scr[m16 * 36 + quad * 8]);
#pragma unroll
      for (int ntc = 0; ntc < 2; ++ntc) {
        bf16x8 bvv = lds8(&Vt[(ntc * 16 + m16) * VT_PITCH + k7 * 32 + quad * 8]);
        avacc[ntc] = __builtin_amdgcn_mfma_f32_16x16x32_bf16(ap, bvv, avacc[ntc], 0, 0, 0);
      }
    }
    float inv[4];
#pragma unroll
    for (int r = 0; r < 4; ++r) {
      rs[r] += __shfl_xor(rs[r], 1);
      rs[r] += __shfl_xor(rs[r], 2);
      rs[r] += __shfl_xor(rs[r], 4);
      rs[r] += __shfl_xor(rs[r], 8);
      // padding agents (>=49) have rs==0; force inv=0 so AVt cols stay 0 (not NaN)
      inv[r] = (16 * w + quad * 4 + r < 49) ? 1.f / rs[r] : 0.f;
    }
#pragma unroll
    for (int ntc = 0; ntc < 2; ++ntc)
#pragma unroll
      for (int r = 0; r < 4; ++r)
        AVt[(ntc * 16 + m16) * 68 + 16 * w + quad * 4 + r] = f2bf(avacc[ntc][r] * inv[r]);
  }

  // ===== Phase C2: depthwise 3x3 from Vt -> dwcs (thread = ch x slot8, even pairs) =====
  {
    int ch = tid & 31, slot = tid >> 5;
    const u16* Vr = &Vt[ch * VT_PITCH];
    float wv[10];
#pragma unroll
    for (int tp = 0; tp < 10; ++tp) wv[tp] = bf2f(dwcw[tp * 32 + ch]);
    for (int p = slot; p < 98; p += 8) {
      int t0 = 2 * p;
      int y = t0 / 14, x0 = t0 % 14;               // x0 even
      float a0 = wv[9], a1 = wv[9];                // conv bias
#pragma unroll
      for (int dy = -1; dy <= 1; ++dy) {
        int yy = y + dy;
        if (yy < 0 || yy > 13) continue;
        int tb = yy * 14 + x0;
        float wl = wv[(dy + 1) * 3], wc = wv[(dy + 1) * 3 + 1], wr = wv[(dy + 1) * 3 + 2];
        u32 vm = *(const u32*)(Vr + tb);
        float vx0 = bf2f((u16)(vm & 0xffff)), vx1 = bf2f((u16)(vm >> 16));
        float vxm1 = 0.f, vx2 = 0.f;
        if (x0 > 0)  { u32 vl = *(const u32*)(Vr + tb - 2); vxm1 = bf2f((u16)(vl >> 16)); }
        if (x0 < 12) { u32 vr2 = *(const u32*)(Vr + tb + 2); vx2 = bf2f((u16)(vr2 & 0xffff)); }
        a0 += wl * vxm1 + wc * vx0 + wr * vx1;
        a1 += wl * vx0  + wc * vx1 + wr * vx2;
      }
      dwcs[t0 * 32 + ch]       = f2bf(a0);
      dwcs[(t0 + 1) * 32 + ch] = f2bf(a1);
    }
  }
  __syncthreads();  // AVt/dwcs ready for all waves; Vt dead -> P2w region usable

  // ===== Phase D+E: per m-tile: S2 softmax -> P2w -> Out = P2 @ AV (+dwc) -> t =====
  const u16* b2 = b2t + (long)h * 49 * 196;
  for (int mt = w; mt < 13; mt += 4) {
    int tka = mt * 16 + m16; if (tka > 195) tka = 195;
    bf16x8 aq = *(const bf16x8*)(qkv + qkvb + (long)tka * 1152 + h * 32 + quad * 8);
    f32x4 sacc[4];
#pragma unroll
    for (int nt = 0; nt < 4; ++nt) {
      int gr = nt * 16 + m16; if (gr > 48) gr = 48;   // clamped dup, masked below
      bf16x8 bv = lds8(&ags[gr * 36 + quad * 8]);
      sacc[nt] = __builtin_amdgcn_mfma_f32_16x16x32_bf16(aq, bv, zf, 0, 0, 0);
    }
    int tb = mt * 16 + quad * 4; if (tb > 192) tb = 192;  // keep loads in-row, finite
    float rs[4] = {0.f, 0.f, 0.f, 0.f};
#pragma unroll
    for (int nt = 0; nt < 4; ++nt) {
      int agent = nt * 16 + m16;
      union { uint2 v; u16 s4[4]; } bb;
      bb.v = *(const uint2*)(b2 + agent * 196 + tb);     // b2t padded for agent>=49
#pragma unroll
      for (int r = 0; r < 4; ++r) {
        float e = 0.f;
        if (agent < 49)
          e = __expf(sacc[nt][r] * SCALE + bf2f(bb.s4[r]));
        sacc[nt][r] = e;
        rs[r] += e;
      }
    }
    float inv[4];
#pragma unroll
    for (int r = 0; r < 4; ++r) {
      rs[r] += __shfl_xor(rs[r], 1);
      rs[r] += __shfl_xor(rs[r], 2);
      rs[r] += __shfl_xor(rs[r], 4);
      rs[r] += __shfl_xor(rs[r], 8);
      inv[r] = 1.f / rs[r];
    }
#pragma unroll
    for (int nt = 0; nt < 4; ++nt)
#pragma unroll
      for (int r = 0; r < 4; ++r)
        P2w[(quad * 4 + r) * 68 + nt * 16 + m16] = f2bf(sacc[nt][r] * inv[r]);
    // Out = P2 @ AV  (same-wave LDS write->read: DS is in-order per wave)
    f32x4 oacc[2] = {zf, zf};
#pragma unroll
    for (int k2 = 0; k2 < 2; ++k2) {
      bf16x8 ap = lds8(&P2w[m16 * 68 + k2 * 32 + quad * 8]);
#pragma unroll
      for (int nt2 = 0; nt2 < 2; ++nt2) {
        bf16x8 bv = lds8(&AVt[(nt2 * 16 + m16) * 68 + k2 * 32 + quad * 8]);
        oacc[nt2] = __builtin_amdgcn_mfma_f32_16x16x32_bf16(ap, bv, oacc[nt2], 0, 0, 0);
      }
    }
#pragma unroll
    for (int nt2 = 0; nt2 < 2; ++nt2)
#pragma unroll
      for (int r = 0; r < 4; ++r) {
        int token = mt * 16 + quad * 4 + r;
        if (token < 196) {
          int ch = nt2 * 16 + m16;
          float val = oacc[nt2][r] + bf2f(dwcs[token * 32 + ch]);
          t[((long)(b * 196 + token)) * 384 + h * 32 + ch] = f2bf(val);
        }
      }
  }
}

extern "C" void kernel_launch(void* const* d_in, const int* in_sizes, int n_in,
                              void* d_out, int out_size, void* d_ws, size_t ws_size,
                              hipStream_t stream) {
  (void)in_sizes; (void)n_in; (void)out_size; (void)ws_size;
  const float* x      = (const float*)d_in[0];
  const float* qkv_w  = (const float*)d_in[1];
  const float* proj_w = (const float*)d_in[2];
  const float* proj_b = (const float*)d_in[3];
  const float* dwc_w  = (const float*)d_in[4];
  const float* dwc_b  = (const float*)d_in[5];
  const float* an_b   = (const float*)d_in[6];
  const float* ah_b   = (const float*)d_in[7];
  const float* aw_b   = (const float*)d_in[8];
  const float* na_b   = (const float*)d_in[9];
  const float* ha_b   = (const float*)d_in[10];
  const float* wa_b   = (const float*)d_in[11];
  float* out = (float*)d_out;

  // workspace layout (bytes); xb eliminated (x converted in-GEMM now)
  char* ws = (char*)d_ws;
  u16*   qkv     = (u16*)ws;                       // 231,211,008
  u16*   t       = (u16*)(ws + 231211008);         //  77,070,336
  u16*   wqkvb   = (u16*)(ws + 308281344);         //     884,736
  u16*   wprojb  = (u16*)(ws + 309166080);         //     294,912
  u16*   b1t     = (u16*)(ws + 309460992);         //     244,608 + pad
  u16*   b2t     = (u16*)(ws + 309707008);         //     230,496 + pad

  k_bias1<<<478, 256, 0, stream>>>(an_b, ah_b, aw_b, b1t);
  k_bias2<<<451, 256, 0, stream>>>(na_b, ha_b, wa_b, b2t);
  k_f2bf<<<216, 256, 0, stream>>>(qkv_w, wqkvb, (long)1152 * 384);
  k_f2bf<<<72, 256, 0, stream>>>(proj_w, wprojb, (long)384 * 384);
  k_mfma_qkv<<<7056, 256, 0, stream>>>(x, wqkvb, qkv);
  k_fused<<<6144, 256, 0, stream>>>(qkv, b1t, b2t, dwc_w, dwc_b, t);
  k_mfma_out<<<2352, 256, 0, stream>>>(t, wprojb, proj_b, out);
}